// Round 9
// baseline (1058.459 us; speedup 1.0000x reference)
//
#include <hip/hip_runtime.h>

typedef short s16x8 __attribute__((ext_vector_type(8)));  // 8 bf16 (guide-verified spelling)
typedef float f32x4 __attribute__((ext_vector_type(4)));

#define CODES_ELEMS 8388608   // 16*1024*512
#define N_ROWS      131072    // 16*1024*8
#define IDX_OFF     CODES_ELEMS
#define LOSS_OFF    (CODES_ELEMS + N_ROWS)

// d_ws: [0,4) loss acc; [64,8256) cc[2048];
// [8448,532736) cbs bf16-split tiled codebook [chunk16][seg4][ct8][lane64][8];
// [532736,663808) per-row flag bytes (131072)
#define WS_LOSS 0
#define WS_CC   64
#define WS_CBS  8448
#define WS_FLAG 532736
#define MARGIN_T 0.25f

__device__ __forceinline__ float bf2f(unsigned short h) { return __uint_as_float(((unsigned)h) << 16); }
__device__ __forceinline__ unsigned short f2bf(float f) {   // RNE
  unsigned u = __float_as_uint(f);
  u += 0x7fffu + ((u >> 16) & 1u);
  return (unsigned short)(u >> 16);
}

// cc[k] = sum_d c^2 (butterfly chain identical to rounds 4-7); zero loss.
__global__ __launch_bounds__(256) void vq_prep1(const float* __restrict__ cb,
                                                float* __restrict__ cc,
                                                float* __restrict__ loss) {
  int t = threadIdx.x;
  if (blockIdx.x == 0 && t == 0) loss[0] = 0.f;
  int e = blockIdx.x * 256 + t;          // 512*256 = 2048 codes * 64 dims
  float v = cb[e];
  float s = v * v;
  #pragma unroll
  for (int m = 1; m < 64; m <<= 1) s += __shfl_xor(s, m, 64);
  if ((t & 63) == 0) cc[e >> 6] = s;
}

// bf16 split of codebook into MFMA-B-fragment tiled layout.
// segs 0,1 = c1 (dims 0-31, 32-63); segs 2,3 = c2 residual. lane = q*16 + n.
__global__ __launch_bounds__(256) void vq_prep2(const float* __restrict__ cb,
                                                unsigned short* __restrict__ cbs) {
  int e = blockIdx.x * 256 + threadIdx.x;   // 1024*256 = 2048 codes * 128 K-elems
  int k = e >> 7, K = e & 127;
  int s = K >> 5, rem = K & 31, q = rem >> 3, j = rem & 7;
  int d = (s < 2) ? K : (K - 64);
  float c = cb[k * 64 + d];
  unsigned short c1 = f2bf(c);
  unsigned short val = (s < 2) ? c1 : f2bf(c - bf2f(c1));  // exact residual split
  int chunk = k >> 7, ct = (k >> 4) & 7, n = k & 15;
  cbs[(((chunk * 4 + s) * 8 + ct) * 64 + (q * 16 + n)) * 8 + j] = val;
}

// Main: block = 64 rows x 2048 codes. approx dist = cc + MFMA(-2z split, c split)
// (zz omitted: row-constant, argmin/margin invariant). Track best+second; flag
// rows with margin < T into the flag array; write approx argmin for all rows.
__global__ __launch_bounds__(256) void VQQuantizer_30064771072206_kernel(
    const float* __restrict__ zf, const unsigned short* __restrict__ cbs,
    const float* __restrict__ cc, unsigned char* __restrict__ flags,
    float* __restrict__ out)
{
  __shared__ __align__(16) unsigned short bt[24576];  // 49152 B: [seg6][ct8][lane64][8]
  __shared__ float cc_l[128];
  const int t = threadIdx.x, w = t >> 6, l = t & 63;
  const int col = l & 15, q = l >> 4;
  const int R0 = blockIdx.x * 64;
  const float4* zf4 = (const float4*)zf;

  // A-fragments: lane holds A[m=l&15][k=q*8+j]; m -> z row R0+16w+m.
  s16x8 az1[2], az2[2];
  {
    int row = R0 + 16 * w + col;
    const float4* zr = zf4 + (size_t)row * 16;
    #pragma unroll
    for (int s = 0; s < 2; ++s) {
      float4 u0 = zr[s * 8 + q * 2];
      float4 u1 = zr[s * 8 + q * 2 + 1];
      float m2[8] = {-2.f*u0.x, -2.f*u0.y, -2.f*u0.z, -2.f*u0.w,
                     -2.f*u1.x, -2.f*u1.y, -2.f*u1.z, -2.f*u1.w};
      #pragma unroll
      for (int j = 0; j < 8; ++j) {
        unsigned short h1 = f2bf(m2[j]);
        unsigned short h2 = f2bf(m2[j] - bf2f(h1));
        az1[s][j] = (short)h1;
        az2[s][j] = (short)h2;
      }
    }
  }

  float v1[4], v2[4]; int i1[4];
  #pragma unroll
  for (int r = 0; r < 4; ++r) { v1[r] = 3.402823466e38f; v2[r] = 3.402823466e38f; i1[r] = 0; }

  for (int chunk = 0; chunk < 16; ++chunk) {
    if (chunk) __syncthreads();
    #pragma unroll
    for (int i = 0; i < 12; ++i) {        // 3072 16B slots, identity copy
      int f = i * 256 + t;
      int s = f >> 9, ct_ = (f >> 6) & 7, l_ = f & 63;
      int src_s = (s >= 4) ? s - 4 : s;   // segs 4,5 re-read c1 (segs 0,1)
      *(uint4*)&bt[((s * 8 + ct_) * 64 + l_) * 8] =
          *(const uint4*)&cbs[(size_t)chunk * 16384 + (size_t)((src_s * 8 + ct_) * 64 + l_) * 8];
    }
    if (t < 128) cc_l[t] = cc[chunk * 128 + t];
    __syncthreads();

    #pragma unroll
    for (int ct = 0; ct < 8; ++ct) {
      float nh = cc_l[ct * 16 + col];
      f32x4 acc; acc[0] = nh; acc[1] = nh; acc[2] = nh; acc[3] = nh;
      const unsigned short* base = &bt[(ct * 64 + l) * 8];
      // z1*c1 (dims 0-31, 32-63), z1*c2, z2*c1  (z2*c2 dropped, ~1e-4 << T)
      acc = __builtin_amdgcn_mfma_f32_16x16x32_bf16(az1[0], *(const s16x8*)(base + 0 * 4096), acc, 0, 0, 0);
      acc = __builtin_amdgcn_mfma_f32_16x16x32_bf16(az1[1], *(const s16x8*)(base + 1 * 4096), acc, 0, 0, 0);
      acc = __builtin_amdgcn_mfma_f32_16x16x32_bf16(az1[0], *(const s16x8*)(base + 2 * 4096), acc, 0, 0, 0);
      acc = __builtin_amdgcn_mfma_f32_16x16x32_bf16(az1[1], *(const s16x8*)(base + 3 * 4096), acc, 0, 0, 0);
      acc = __builtin_amdgcn_mfma_f32_16x16x32_bf16(az2[0], *(const s16x8*)(base + 4 * 4096), acc, 0, 0, 0);
      acc = __builtin_amdgcn_mfma_f32_16x16x32_bf16(az2[1], *(const s16x8*)(base + 5 * 4096), acc, 0, 0, 0);
      int code = chunk * 128 + ct * 16 + col;
      #pragma unroll
      for (int r = 0; r < 4; ++r) {       // ascending code ids: first-wins ties
        float d = acc[r];
        bool lt = d < v1[r];
        v2[r] = lt ? v1[r] : fminf(v2[r], d);
        i1[r] = lt ? code : i1[r];
        v1[r] = lt ? d : v1[r];
      }
    }
  }

  // merge (best, idx, second) across the 16 lanes {q*16..q*16+15} sharing rows
  #pragma unroll
  for (int r = 0; r < 4; ++r) {
    float a = v1[r], b2 = v2[r]; int ia = i1[r];
    #pragma unroll
    for (int m = 1; m < 16; m <<= 1) {
      float oa = __shfl_xor(a, m, 64);
      int   oi = __shfl_xor(ia, m, 64);
      float ob = __shfl_xor(b2, m, 64);
      float hi = fmaxf(a, oa);
      b2 = fminf(fminf(b2, ob), hi);
      bool take = (oa < a) || (oa == a && oi < ia);
      a = take ? oa : a; ia = take ? oi : ia;
    }
    v1[r] = a; v2[r] = b2; i1[r] = ia;
  }
  if (col == 0) {   // C/D: col=l&15, row=(l>>4)*4+r [m89]; rows q*4+r consecutive
    unsigned pack = 0;
    #pragma unroll
    for (int r = 0; r < 4; ++r) {
      int row = R0 + 16 * w + q * 4 + r;
      out[IDX_OFF + row] = (float)i1[r];
      if (v2[r] - v1[r] < MARGIN_T) pack |= (1u << (8 * r));
    }
    *(unsigned*)&flags[R0 + 16 * w + q * 4] = pack;  // every row written once
  }
}

// Exact rescore of flagged rows: round-4/6/7-validated fp32 chain
// (sequential-d zz and dot, dist = (zz - 2*acc) + cc, first-wins ties).
__global__ __launch_bounds__(256) void vq_rescore(
    const float* __restrict__ zf, const float* __restrict__ cb,
    const float* __restrict__ cc, const unsigned char* __restrict__ flags,
    float* __restrict__ out)
{
  int w = threadIdx.x >> 6, l = threadIdx.x & 63;
  for (int row = blockIdx.x * 4 + w; row < N_ROWS; row += 1024) {
    if (!flags[row]) continue;
    const float* zrow = zf + (size_t)row * 64;
    float zz = 0.f;
    for (int d = 0; d < 64; ++d) { float v = zrow[d]; zz += v * v; }
    float bv = 3.402823466e38f; int bi = 0;
    for (int o = 0; o < 8; ++o) {
      int c0 = l + o * 256;               // per-lane codes ascending overall
      const float* r0 = cb + (size_t)c0 * 64;
      const float* r1 = r0 + 64 * 64;
      const float* r2 = r1 + 64 * 64;
      const float* r3 = r2 + 64 * 64;
      float a0 = 0.f, a1 = 0.f, a2 = 0.f, a3 = 0.f;
      for (int d = 0; d < 64; ++d) {
        float zv = zrow[d];
        a0 += zv * r0[d]; a1 += zv * r1[d]; a2 += zv * r2[d]; a3 += zv * r3[d];
      }
      float t0 = zz - 2.0f * a0; float d0 = t0 + cc[c0];
      if (d0 < bv) { bv = d0; bi = c0; }
      float t1 = zz - 2.0f * a1; float d1 = t1 + cc[c0 + 64];
      if (d1 < bv) { bv = d1; bi = c0 + 64; }
      float t2 = zz - 2.0f * a2; float d2 = t2 + cc[c0 + 128];
      if (d2 < bv) { bv = d2; bi = c0 + 128; }
      float t3 = zz - 2.0f * a3; float d3 = t3 + cc[c0 + 192];
      if (d3 < bv) { bv = d3; bi = c0 + 192; }
    }
    #pragma unroll
    for (int m = 1; m < 64; m <<= 1) {
      float ov = __shfl_xor(bv, m, 64); int oi = __shfl_xor(bi, m, 64);
      if (ov < bv || (ov == bv && oi < bi)) { bv = ov; bi = oi; }
    }
    if (l == 0) out[IDX_OFF + row] = (float)bi;
  }
}

// codes = zg + (zq - zg), commit loss fp32 (validated epilogue, idx from out).
__global__ __launch_bounds__(256) void vq_epilogue(
    const float* __restrict__ zf, const float* __restrict__ cb,
    float* __restrict__ loss, float* __restrict__ out)
{
  __shared__ int idxb[64];
  __shared__ float wsum[4];
  int t = threadIdx.x;
  int R0 = blockIdx.x * 64;
  if (t < 64) idxb[t] = (int)out[IDX_OFF + R0 + t];
  __syncthreads();
  const float4* zf4 = (const float4*)zf;
  const float4* cb4 = (const float4*)cb;
  float4* out4 = (float4*)out;
  float lsum = 0.f;
  #pragma unroll
  for (int i = 0; i < 4; ++i) {
    int f = i * 256 + t;
    int row = f >> 4, dq = f & 15;
    int k = idxb[row];
    float4 qv = cb4[(size_t)k * 16 + dq];
    float4 zv = zf4[(size_t)(R0 + row) * 16 + dq];
    float dx = qv.x - zv.x, dy = qv.y - zv.y, dz = qv.z - zv.z, dw = qv.w - zv.w;
    float4 st; st.x = zv.x + dx; st.y = zv.y + dy; st.z = zv.z + dz; st.w = zv.w + dw;
    out4[(size_t)(R0 + row) * 16 + dq] = st;
    lsum += dx * dx; lsum += dy * dy; lsum += dz * dz; lsum += dw * dw;
  }
  #pragma unroll
  for (int m = 1; m < 64; m <<= 1) lsum += __shfl_xor(lsum, m, 64);
  if ((t & 63) == 0) wsum[t >> 6] = lsum;
  __syncthreads();
  if (t == 0) atomicAdd(loss, wsum[0] + wsum[1] + wsum[2] + wsum[3]);
}

__global__ void vq_finalize(const float* __restrict__ loss, float* __restrict__ out) {
  out[LOSS_OFF] = loss[0] * (1.f / 8388608.f);
}

extern "C" void kernel_launch(void* const* d_in, const int* in_sizes, int n_in,
                              void* d_out, int out_size, void* d_ws, size_t ws_size,
                              hipStream_t stream) {
  const float* z  = (const float*)d_in[0];
  const float* cb = (const float*)d_in[1];
  float* out = (float*)d_out;
  float* loss = (float*)((char*)d_ws + WS_LOSS);
  float* cc   = (float*)((char*)d_ws + WS_CC);
  unsigned short* cbs = (unsigned short*)((char*)d_ws + WS_CBS);
  unsigned char* flags = (unsigned char*)((char*)d_ws + WS_FLAG);

  vq_prep1<<<512, 256, 0, stream>>>(cb, cc, loss);
  vq_prep2<<<1024, 256, 0, stream>>>(cb, cbs);
  VQQuantizer_30064771072206_kernel<<<2048, 256, 0, stream>>>(z, cbs, cc, flags, out);
  vq_rescore<<<256, 256, 0, stream>>>(z, cb, cc, flags, out);
  vq_epilogue<<<2048, 256, 0, stream>>>(z, cb, loss, out);
  vq_finalize<<<1, 1, 0, stream>>>(loss, out);
}

// Round 10
// 742.755 us; speedup vs baseline: 1.4250x; 1.4250x over previous
//
#include <hip/hip_runtime.h>

typedef short s16x8 __attribute__((ext_vector_type(8)));  // 8 bf16 (guide-verified spelling)
typedef float f32x4 __attribute__((ext_vector_type(4)));

#define CODES_ELEMS 8388608   // 16*1024*512
#define N_ROWS      131072    // 16*1024*8
#define IDX_OFF     CODES_ELEMS
#define LOSS_OFF    (CODES_ELEMS + N_ROWS)

// d_ws: [0,4) loss acc; [4,8) flagged count; [64,8256) cc[2048];
// [8448,532736) cbs bf16-split tiled codebook [chunk16][seg4][ct8][lane64][8];
// [532736,1056 KB) flagged-row list (N_ROWS ints, can never overflow)
#define WS_LOSS 0
#define WS_CNT  4
#define WS_CC   64
#define WS_CBS  8448
#define WS_LIST 532736
#define MARGIN_T 0.25f   // validated in round 9 (absmax 0)

__device__ __forceinline__ float bf2f(unsigned short h) { return __uint_as_float(((unsigned)h) << 16); }
__device__ __forceinline__ unsigned short f2bf(float f) {   // RNE
  unsigned u = __float_as_uint(f);
  u += 0x7fffu + ((u >> 16) & 1u);
  return (unsigned short)(u >> 16);
}

// cc[k] = sum_d c^2 (butterfly chain identical to rounds 4-9); zero loss+cnt.
__global__ __launch_bounds__(256) void vq_prep1(const float* __restrict__ cb,
                                                float* __restrict__ cc,
                                                float* __restrict__ loss,
                                                int* __restrict__ cnt) {
  int t = threadIdx.x;
  if (blockIdx.x == 0 && t == 0) { loss[0] = 0.f; cnt[0] = 0; }
  int e = blockIdx.x * 256 + t;          // 512*256 = 2048 codes * 64 dims
  float v = cb[e];
  float s = v * v;
  #pragma unroll
  for (int m = 1; m < 64; m <<= 1) s += __shfl_xor(s, m, 64);
  if ((t & 63) == 0) cc[e >> 6] = s;
}

// bf16 split of codebook into MFMA-B-fragment tiled layout (validated r9).
__global__ __launch_bounds__(256) void vq_prep2(const float* __restrict__ cb,
                                                unsigned short* __restrict__ cbs) {
  int e = blockIdx.x * 256 + threadIdx.x;   // 1024*256 = 2048 codes * 128 K-elems
  int k = e >> 7, K = e & 127;
  int s = K >> 5, rem = K & 31, q = rem >> 3, j = rem & 7;
  int d = (s < 2) ? K : (K - 64);
  float c = cb[k * 64 + d];
  unsigned short c1 = f2bf(c);
  unsigned short val = (s < 2) ? c1 : f2bf(c - bf2f(c1));  // exact residual split
  int chunk = k >> 7, ct = (k >> 4) & 7, n = k & 15;
  cbs[(((chunk * 4 + s) * 8 + ct) * 64 + (q * 16 + n)) * 8 + j] = val;
}

// Main (validated r9, flag path -> direct list append): block = 64 rows x 2048
// codes; approx dist = cc + MFMA(-2z split, c split); best+second tracked;
// margin < T rows appended to list; approx argmin written for all rows.
__global__ __launch_bounds__(256) void VQQuantizer_30064771072206_kernel(
    const float* __restrict__ zf, const unsigned short* __restrict__ cbs,
    const float* __restrict__ cc, int* __restrict__ cnt, int* __restrict__ list,
    float* __restrict__ out)
{
  __shared__ __align__(16) unsigned short bt[24576];  // 49152 B: [seg6][ct8][lane64][8]
  __shared__ float cc_l[128];
  const int t = threadIdx.x, w = t >> 6, l = t & 63;
  const int col = l & 15, q = l >> 4;
  const int R0 = blockIdx.x * 64;
  const float4* zf4 = (const float4*)zf;

  // A-fragments: lane holds A[m=l&15][k=q*8+j]; m -> z row R0+16w+m.
  s16x8 az1[2], az2[2];
  {
    int row = R0 + 16 * w + col;
    const float4* zr = zf4 + (size_t)row * 16;
    #pragma unroll
    for (int s = 0; s < 2; ++s) {
      float4 u0 = zr[s * 8 + q * 2];
      float4 u1 = zr[s * 8 + q * 2 + 1];
      float m2[8] = {-2.f*u0.x, -2.f*u0.y, -2.f*u0.z, -2.f*u0.w,
                     -2.f*u1.x, -2.f*u1.y, -2.f*u1.z, -2.f*u1.w};
      #pragma unroll
      for (int j = 0; j < 8; ++j) {
        unsigned short h1 = f2bf(m2[j]);
        unsigned short h2 = f2bf(m2[j] - bf2f(h1));
        az1[s][j] = (short)h1;
        az2[s][j] = (short)h2;
      }
    }
  }

  float v1[4], v2[4]; int i1[4];
  #pragma unroll
  for (int r = 0; r < 4; ++r) { v1[r] = 3.402823466e38f; v2[r] = 3.402823466e38f; i1[r] = 0; }

  for (int chunk = 0; chunk < 16; ++chunk) {
    if (chunk) __syncthreads();
    #pragma unroll
    for (int i = 0; i < 12; ++i) {        // 3072 16B slots, identity copy
      int f = i * 256 + t;
      int s = f >> 9, ct_ = (f >> 6) & 7, l_ = f & 63;
      int src_s = (s >= 4) ? s - 4 : s;   // segs 4,5 re-read c1 (segs 0,1)
      *(uint4*)&bt[((s * 8 + ct_) * 64 + l_) * 8] =
          *(const uint4*)&cbs[(size_t)chunk * 16384 + (size_t)((src_s * 8 + ct_) * 64 + l_) * 8];
    }
    if (t < 128) cc_l[t] = cc[chunk * 128 + t];
    __syncthreads();

    #pragma unroll
    for (int ct = 0; ct < 8; ++ct) {
      float nh = cc_l[ct * 16 + col];
      f32x4 acc; acc[0] = nh; acc[1] = nh; acc[2] = nh; acc[3] = nh;
      const unsigned short* base = &bt[(ct * 64 + l) * 8];
      // z1*c1 (dims 0-31, 32-63), z1*c2, z2*c1  (z2*c2 dropped << T)
      acc = __builtin_amdgcn_mfma_f32_16x16x32_bf16(az1[0], *(const s16x8*)(base + 0 * 4096), acc, 0, 0, 0);
      acc = __builtin_amdgcn_mfma_f32_16x16x32_bf16(az1[1], *(const s16x8*)(base + 1 * 4096), acc, 0, 0, 0);
      acc = __builtin_amdgcn_mfma_f32_16x16x32_bf16(az1[0], *(const s16x8*)(base + 2 * 4096), acc, 0, 0, 0);
      acc = __builtin_amdgcn_mfma_f32_16x16x32_bf16(az1[1], *(const s16x8*)(base + 3 * 4096), acc, 0, 0, 0);
      acc = __builtin_amdgcn_mfma_f32_16x16x32_bf16(az2[0], *(const s16x8*)(base + 4 * 4096), acc, 0, 0, 0);
      acc = __builtin_amdgcn_mfma_f32_16x16x32_bf16(az2[1], *(const s16x8*)(base + 5 * 4096), acc, 0, 0, 0);
      int code = chunk * 128 + ct * 16 + col;
      #pragma unroll
      for (int r = 0; r < 4; ++r) {       // ascending code ids: first-wins ties
        float d = acc[r];
        bool lt = d < v1[r];
        v2[r] = lt ? v1[r] : fminf(v2[r], d);
        i1[r] = lt ? code : i1[r];
        v1[r] = lt ? d : v1[r];
      }
    }
  }

  // merge (best, idx, second) across the 16 lanes {q*16..q*16+15} sharing rows
  #pragma unroll
  for (int r = 0; r < 4; ++r) {
    float a = v1[r], b2 = v2[r]; int ia = i1[r];
    #pragma unroll
    for (int m = 1; m < 16; m <<= 1) {
      float oa = __shfl_xor(a, m, 64);
      int   oi = __shfl_xor(ia, m, 64);
      float ob = __shfl_xor(b2, m, 64);
      float hi = fmaxf(a, oa);
      b2 = fminf(fminf(b2, ob), hi);
      bool take = (oa < a) || (oa == a && oi < ia);
      a = take ? oa : a; ia = take ? oi : ia;
    }
    v1[r] = a; v2[r] = b2; i1[r] = ia;
  }
  if (col == 0) {   // C/D: col=l&15, row=(l>>4)*4+r [m89]
    #pragma unroll
    for (int r = 0; r < 4; ++r) {
      int row = R0 + 16 * w + q * 4 + r;
      out[IDX_OFF + row] = (float)i1[r];
      if (v2[r] - v1[r] < MARGIN_T) {
        int p = atomicAdd(cnt, 1);        // <= N_ROWS appends, no overflow
        list[p] = row;
      }
    }
  }
}

// Rescore v2: one BLOCK per flagged row (grid-strided over the compacted
// list). Exact np chain per code: zz sequential-d, dot sequential-d,
// dist = (zz - 2a) + cc, first-wins ties. 8 indep code-chains per thread.
__global__ __launch_bounds__(256) void vq_rescore(
    const float* __restrict__ zf, const float* __restrict__ cb,
    const float* __restrict__ cc, const int* __restrict__ cnt,
    const int* __restrict__ list, float* __restrict__ out)
{
  __shared__ __align__(16) float zl[64];
  __shared__ float rv[4];
  __shared__ int   ri[4];
  const int t = threadIdx.x, w = t >> 6, l = t & 63;
  const int count = cnt[0];
  const float4* cb4 = (const float4*)cb;

  for (int it = blockIdx.x; it < count; it += 1024) {
    const int row = list[it];
    if (it != blockIdx.x) __syncthreads();   // zl consumed by previous iter
    if (t < 16) *(float4*)&zl[t * 4] = ((const float4*)zf)[(size_t)row * 16 + t];
    __syncthreads();

    // zz: sequential-d chain (identical to validated rounds); broadcast reads
    float zz = 0.f;
    for (int d = 0; d < 64; ++d) { float v = zl[d]; zz += v * v; }

    // 8 codes per thread: t, 256+t, ... (ascending); float4 loads, scalar chain
    float bv = 3.402823466e38f; int bi = 0;
    #pragma unroll
    for (int o = 0; o < 8; ++o) {
      int c = o * 256 + t;
      const float4* cr = cb4 + (size_t)c * 16;
      float a = 0.f;
      #pragma unroll
      for (int dq = 0; dq < 16; ++dq) {
        float4 cv = cr[dq];
        a += zl[dq * 4 + 0] * cv.x;          // ascending d, one fused chain
        a += zl[dq * 4 + 1] * cv.y;
        a += zl[dq * 4 + 2] * cv.z;
        a += zl[dq * 4 + 3] * cv.w;
      }
      float t0 = zz - 2.0f * a;
      float dist = t0 + cc[c];
      if (dist < bv) { bv = dist; bi = c; }  // ascending c: first-wins
    }
    // wave reduce then cross-wave via LDS; (v, lowest idx) semantics
    #pragma unroll
    for (int m = 1; m < 64; m <<= 1) {
      float ov = __shfl_xor(bv, m, 64); int oi = __shfl_xor(bi, m, 64);
      if (ov < bv || (ov == bv && oi < bi)) { bv = ov; bi = oi; }
    }
    if (l == 0) { rv[w] = bv; ri[w] = bi; }
    __syncthreads();
    if (t == 0) {
      float fv = rv[0]; int fi = ri[0];
      #pragma unroll
      for (int k = 1; k < 4; ++k) {
        if (rv[k] < fv || (rv[k] == fv && ri[k] < fi)) { fv = rv[k]; fi = ri[k]; }
      }
      out[IDX_OFF + row] = (float)fi;
    }
  }
}

// codes = zg + (zq - zg), commit loss fp32 (validated epilogue, idx from out).
__global__ __launch_bounds__(256) void vq_epilogue(
    const float* __restrict__ zf, const float* __restrict__ cb,
    float* __restrict__ loss, float* __restrict__ out)
{
  __shared__ int idxb[64];
  __shared__ float wsum[4];
  int t = threadIdx.x;
  int R0 = blockIdx.x * 64;
  if (t < 64) idxb[t] = (int)out[IDX_OFF + R0 + t];
  __syncthreads();
  const float4* zf4 = (const float4*)zf;
  const float4* cb4 = (const float4*)cb;
  float4* out4 = (float4*)out;
  float lsum = 0.f;
  #pragma unroll
  for (int i = 0; i < 4; ++i) {
    int f = i * 256 + t;
    int row = f >> 4, dq = f & 15;
    int k = idxb[row];
    float4 qv = cb4[(size_t)k * 16 + dq];
    float4 zv = zf4[(size_t)(R0 + row) * 16 + dq];
    float dx = qv.x - zv.x, dy = qv.y - zv.y, dz = qv.z - zv.z, dw = qv.w - zv.w;
    float4 st; st.x = zv.x + dx; st.y = zv.y + dy; st.z = zv.z + dz; st.w = zv.w + dw;
    out4[(size_t)(R0 + row) * 16 + dq] = st;
    lsum += dx * dx; lsum += dy * dy; lsum += dz * dz; lsum += dw * dw;
  }
  #pragma unroll
  for (int m = 1; m < 64; m <<= 1) lsum += __shfl_xor(lsum, m, 64);
  if ((t & 63) == 0) wsum[t >> 6] = lsum;
  __syncthreads();
  if (t == 0) atomicAdd(loss, wsum[0] + wsum[1] + wsum[2] + wsum[3]);
}

__global__ void vq_finalize(const float* __restrict__ loss, float* __restrict__ out) {
  out[LOSS_OFF] = loss[0] * (1.f / 8388608.f);
}

extern "C" void kernel_launch(void* const* d_in, const int* in_sizes, int n_in,
                              void* d_out, int out_size, void* d_ws, size_t ws_size,
                              hipStream_t stream) {
  const float* z  = (const float*)d_in[0];
  const float* cb = (const float*)d_in[1];
  float* out = (float*)d_out;
  float* loss = (float*)((char*)d_ws + WS_LOSS);
  int*   cnt  = (int*)((char*)d_ws + WS_CNT);
  float* cc   = (float*)((char*)d_ws + WS_CC);
  unsigned short* cbs = (unsigned short*)((char*)d_ws + WS_CBS);
  int*   list = (int*)((char*)d_ws + WS_LIST);

  vq_prep1<<<512, 256, 0, stream>>>(cb, cc, loss, cnt);
  vq_prep2<<<1024, 256, 0, stream>>>(cb, cbs);
  VQQuantizer_30064771072206_kernel<<<2048, 256, 0, stream>>>(z, cbs, cc, cnt, list, out);
  vq_rescore<<<1024, 256, 0, stream>>>(z, cb, cc, cnt, list, out);
  vq_epilogue<<<2048, 256, 0, stream>>>(z, cb, loss, out);
  vq_finalize<<<1, 1, 0, stream>>>(loss, out);
}

// Round 11
// 387.579 us; speedup vs baseline: 2.7310x; 1.9164x over previous
//
#include <hip/hip_runtime.h>

typedef short s16x8 __attribute__((ext_vector_type(8)));  // 8 bf16 (guide-verified spelling)
typedef float f32x4 __attribute__((ext_vector_type(4)));

#define CODES_ELEMS 8388608   // 16*1024*512
#define N_ROWS      131072    // 16*1024*8
#define IDX_OFF     CODES_ELEMS
#define LOSS_OFF    (CODES_ELEMS + N_ROWS)

// d_ws: [0,4) loss acc; [4,8) flagged count; [64,8256) cc[2048];
// [8448,532736) cbs bf16-split tiled codebook [chunk16][seg4][ct8][lane64][8];
// [532736,1056 KB) flagged-row list (N_ROWS ints, can never overflow)
#define WS_LOSS 0
#define WS_CNT  4
#define WS_CC   64
#define WS_CBS  8448
#define WS_LIST 532736
// T=0.05: ~50x the analytic approx-error bound (~1e-3); flags ~1.25% of rows.
// r9/r10 passed at T=0.25 (empirical error ceiling); r8's failure was the
// asm-hazard/CAP paths, both removed.
#define MARGIN_T 0.05f

__device__ __forceinline__ float bf2f(unsigned short h) { return __uint_as_float(((unsigned)h) << 16); }
__device__ __forceinline__ unsigned short f2bf(float f) {   // RNE
  unsigned u = __float_as_uint(f);
  u += 0x7fffu + ((u >> 16) & 1u);
  return (unsigned short)(u >> 16);
}

// cc[k] = sum_d c^2 (butterfly chain identical to rounds 4-10); zero loss+cnt.
__global__ __launch_bounds__(256) void vq_prep1(const float* __restrict__ cb,
                                                float* __restrict__ cc,
                                                float* __restrict__ loss,
                                                int* __restrict__ cnt) {
  int t = threadIdx.x;
  if (blockIdx.x == 0 && t == 0) { loss[0] = 0.f; cnt[0] = 0; }
  int e = blockIdx.x * 256 + t;          // 512*256 = 2048 codes * 64 dims
  float v = cb[e];
  float s = v * v;
  #pragma unroll
  for (int m = 1; m < 64; m <<= 1) s += __shfl_xor(s, m, 64);
  if ((t & 63) == 0) cc[e >> 6] = s;
}

// bf16 split of codebook into MFMA-B-fragment tiled layout (validated r9/r10).
__global__ __launch_bounds__(256) void vq_prep2(const float* __restrict__ cb,
                                                unsigned short* __restrict__ cbs) {
  int e = blockIdx.x * 256 + threadIdx.x;   // 1024*256 = 2048 codes * 128 K-elems
  int k = e >> 7, K = e & 127;
  int s = K >> 5, rem = K & 31, q = rem >> 3, j = rem & 7;
  int d = (s < 2) ? K : (K - 64);
  float c = cb[k * 64 + d];
  unsigned short c1 = f2bf(c);
  unsigned short val = (s < 2) ? c1 : f2bf(c - bf2f(c1));  // exact residual split
  int chunk = k >> 7, ct = (k >> 4) & 7, n = k & 15;
  cbs[(((chunk * 4 + s) * 8 + ct) * 64 + (q * 16 + n)) * 8 + j] = val;
}

// Main (validated r9/r10): block = 64 rows x 2048 codes; approx dist =
// cc + MFMA(-2z split, c split); best+second tracked; margin < T rows
// appended to list; approx argmin written for all rows.
__global__ __launch_bounds__(256) void VQQuantizer_30064771072206_kernel(
    const float* __restrict__ zf, const unsigned short* __restrict__ cbs,
    const float* __restrict__ cc, int* __restrict__ cnt, int* __restrict__ list,
    float* __restrict__ out)
{
  __shared__ __align__(16) unsigned short bt[24576];  // 49152 B: [seg6][ct8][lane64][8]
  __shared__ float cc_l[128];
  const int t = threadIdx.x, w = t >> 6, l = t & 63;
  const int col = l & 15, q = l >> 4;
  const int R0 = blockIdx.x * 64;
  const float4* zf4 = (const float4*)zf;

  // A-fragments: lane holds A[m=l&15][k=q*8+j]; m -> z row R0+16w+m.
  s16x8 az1[2], az2[2];
  {
    int row = R0 + 16 * w + col;
    const float4* zr = zf4 + (size_t)row * 16;
    #pragma unroll
    for (int s = 0; s < 2; ++s) {
      float4 u0 = zr[s * 8 + q * 2];
      float4 u1 = zr[s * 8 + q * 2 + 1];
      float m2[8] = {-2.f*u0.x, -2.f*u0.y, -2.f*u0.z, -2.f*u0.w,
                     -2.f*u1.x, -2.f*u1.y, -2.f*u1.z, -2.f*u1.w};
      #pragma unroll
      for (int j = 0; j < 8; ++j) {
        unsigned short h1 = f2bf(m2[j]);
        unsigned short h2 = f2bf(m2[j] - bf2f(h1));
        az1[s][j] = (short)h1;
        az2[s][j] = (short)h2;
      }
    }
  }

  float v1[4], v2[4]; int i1[4];
  #pragma unroll
  for (int r = 0; r < 4; ++r) { v1[r] = 3.402823466e38f; v2[r] = 3.402823466e38f; i1[r] = 0; }

  for (int chunk = 0; chunk < 16; ++chunk) {
    if (chunk) __syncthreads();
    #pragma unroll
    for (int i = 0; i < 12; ++i) {        // 3072 16B slots, identity copy
      int f = i * 256 + t;
      int s = f >> 9, ct_ = (f >> 6) & 7, l_ = f & 63;
      int src_s = (s >= 4) ? s - 4 : s;   // segs 4,5 re-read c1 (segs 0,1)
      *(uint4*)&bt[((s * 8 + ct_) * 64 + l_) * 8] =
          *(const uint4*)&cbs[(size_t)chunk * 16384 + (size_t)((src_s * 8 + ct_) * 64 + l_) * 8];
    }
    if (t < 128) cc_l[t] = cc[chunk * 128 + t];
    __syncthreads();

    #pragma unroll
    for (int ct = 0; ct < 8; ++ct) {
      float nh = cc_l[ct * 16 + col];
      f32x4 acc; acc[0] = nh; acc[1] = nh; acc[2] = nh; acc[3] = nh;
      const unsigned short* base = &bt[(ct * 64 + l) * 8];
      // z1*c1 (dims 0-31, 32-63), z1*c2, z2*c1  (z2*c2 dropped << T)
      acc = __builtin_amdgcn_mfma_f32_16x16x32_bf16(az1[0], *(const s16x8*)(base + 0 * 4096), acc, 0, 0, 0);
      acc = __builtin_amdgcn_mfma_f32_16x16x32_bf16(az1[1], *(const s16x8*)(base + 1 * 4096), acc, 0, 0, 0);
      acc = __builtin_amdgcn_mfma_f32_16x16x32_bf16(az1[0], *(const s16x8*)(base + 2 * 4096), acc, 0, 0, 0);
      acc = __builtin_amdgcn_mfma_f32_16x16x32_bf16(az1[1], *(const s16x8*)(base + 3 * 4096), acc, 0, 0, 0);
      acc = __builtin_amdgcn_mfma_f32_16x16x32_bf16(az2[0], *(const s16x8*)(base + 4 * 4096), acc, 0, 0, 0);
      acc = __builtin_amdgcn_mfma_f32_16x16x32_bf16(az2[1], *(const s16x8*)(base + 5 * 4096), acc, 0, 0, 0);
      int code = chunk * 128 + ct * 16 + col;
      #pragma unroll
      for (int r = 0; r < 4; ++r) {       // ascending code ids: first-wins ties
        float d = acc[r];
        bool lt = d < v1[r];
        v2[r] = lt ? v1[r] : fminf(v2[r], d);
        i1[r] = lt ? code : i1[r];
        v1[r] = lt ? d : v1[r];
      }
    }
  }

  // merge (best, idx, second) across the 16 lanes {q*16..q*16+15} sharing rows
  #pragma unroll
  for (int r = 0; r < 4; ++r) {
    float a = v1[r], b2 = v2[r]; int ia = i1[r];
    #pragma unroll
    for (int m = 1; m < 16; m <<= 1) {
      float oa = __shfl_xor(a, m, 64);
      int   oi = __shfl_xor(ia, m, 64);
      float ob = __shfl_xor(b2, m, 64);
      float hi = fmaxf(a, oa);
      b2 = fminf(fminf(b2, ob), hi);
      bool take = (oa < a) || (oa == a && oi < ia);
      a = take ? oa : a; ia = take ? oi : ia;
    }
    v1[r] = a; v2[r] = b2; i1[r] = ia;
  }
  if (col == 0) {   // C/D: col=l&15, row=(l>>4)*4+r [m89]
    #pragma unroll
    for (int r = 0; r < 4; ++r) {
      int row = R0 + 16 * w + q * 4 + r;
      out[IDX_OFF + row] = (float)i1[r];
      if (v2[r] - v1[r] < MARGIN_T) {
        int p = atomicAdd(cnt, 1);        // <= N_ROWS appends, no overflow
        list[p] = row;
      }
    }
  }
}

// Rescore (validated r10): one block per flagged row; exact np chain.
// #pragma unroll 1 on the o-loop keeps VGPR low (r10 hit 256 VGPRs).
__global__ __launch_bounds__(256) void vq_rescore(
    const float* __restrict__ zf, const float* __restrict__ cb,
    const float* __restrict__ cc, const int* __restrict__ cnt,
    const int* __restrict__ list, float* __restrict__ out)
{
  __shared__ __align__(16) float zl[64];
  __shared__ float rv[4];
  __shared__ int   ri[4];
  const int t = threadIdx.x, w = t >> 6, l = t & 63;
  const int count = cnt[0];
  const float4* cb4 = (const float4*)cb;

  for (int it = blockIdx.x; it < count; it += 1024) {
    const int row = list[it];
    if (it != blockIdx.x) __syncthreads();   // zl consumed by previous iter
    if (t < 16) *(float4*)&zl[t * 4] = ((const float4*)zf)[(size_t)row * 16 + t];
    __syncthreads();

    // zz: sequential-d chain (identical to validated rounds); broadcast reads
    float zz = 0.f;
    for (int d = 0; d < 64; ++d) { float v = zl[d]; zz += v * v; }

    // 8 codes per thread: t, 256+t, ... (ascending); float4 loads, scalar chain
    float bv = 3.402823466e38f; int bi = 0;
    #pragma unroll 1
    for (int o = 0; o < 8; ++o) {
      int c = o * 256 + t;
      const float4* cr = cb4 + (size_t)c * 16;
      float a = 0.f;
      #pragma unroll
      for (int dq = 0; dq < 16; ++dq) {
        float4 cv = cr[dq];
        a += zl[dq * 4 + 0] * cv.x;          // ascending d, one fused chain
        a += zl[dq * 4 + 1] * cv.y;
        a += zl[dq * 4 + 2] * cv.z;
        a += zl[dq * 4 + 3] * cv.w;
      }
      float t0 = zz - 2.0f * a;
      float dist = t0 + cc[c];
      if (dist < bv) { bv = dist; bi = c; }  // ascending c: first-wins
    }
    // wave reduce then cross-wave via LDS; (v, lowest idx) semantics
    #pragma unroll
    for (int m = 1; m < 64; m <<= 1) {
      float ov = __shfl_xor(bv, m, 64); int oi = __shfl_xor(bi, m, 64);
      if (ov < bv || (ov == bv && oi < bi)) { bv = ov; bi = oi; }
    }
    if (l == 0) { rv[w] = bv; ri[w] = bi; }
    __syncthreads();
    if (t == 0) {
      float fv = rv[0]; int fi = ri[0];
      #pragma unroll
      for (int k = 1; k < 4; ++k) {
        if (rv[k] < fv || (rv[k] == fv && ri[k] < fi)) { fv = rv[k]; fi = ri[k]; }
      }
      out[IDX_OFF + row] = (float)fi;
    }
  }
}

// codes = zg + (zq - zg), commit loss fp32 (validated epilogue, idx from out).
__global__ __launch_bounds__(256) void vq_epilogue(
    const float* __restrict__ zf, const float* __restrict__ cb,
    float* __restrict__ loss, float* __restrict__ out)
{
  __shared__ int idxb[64];
  __shared__ float wsum[4];
  int t = threadIdx.x;
  int R0 = blockIdx.x * 64;
  if (t < 64) idxb[t] = (int)out[IDX_OFF + R0 + t];
  __syncthreads();
  const float4* zf4 = (const float4*)zf;
  const float4* cb4 = (const float4*)cb;
  float4* out4 = (float4*)out;
  float lsum = 0.f;
  #pragma unroll
  for (int i = 0; i < 4; ++i) {
    int f = i * 256 + t;
    int row = f >> 4, dq = f & 15;
    int k = idxb[row];
    float4 qv = cb4[(size_t)k * 16 + dq];
    float4 zv = zf4[(size_t)(R0 + row) * 16 + dq];
    float dx = qv.x - zv.x, dy = qv.y - zv.y, dz = qv.z - zv.z, dw = qv.w - zv.w;
    float4 st; st.x = zv.x + dx; st.y = zv.y + dy; st.z = zv.z + dz; st.w = zv.w + dw;
    out4[(size_t)(R0 + row) * 16 + dq] = st;
    lsum += dx * dx; lsum += dy * dy; lsum += dz * dz; lsum += dw * dw;
  }
  #pragma unroll
  for (int m = 1; m < 64; m <<= 1) lsum += __shfl_xor(lsum, m, 64);
  if ((t & 63) == 0) wsum[t >> 6] = lsum;
  __syncthreads();
  if (t == 0) atomicAdd(loss, wsum[0] + wsum[1] + wsum[2] + wsum[3]);
}

__global__ void vq_finalize(const float* __restrict__ loss, float* __restrict__ out) {
  out[LOSS_OFF] = loss[0] * (1.f / 8388608.f);
}

extern "C" void kernel_launch(void* const* d_in, const int* in_sizes, int n_in,
                              void* d_out, int out_size, void* d_ws, size_t ws_size,
                              hipStream_t stream) {
  const float* z  = (const float*)d_in[0];
  const float* cb = (const float*)d_in[1];
  float* out = (float*)d_out;
  float* loss = (float*)((char*)d_ws + WS_LOSS);
  int*   cnt  = (int*)((char*)d_ws + WS_CNT);
  float* cc   = (float*)((char*)d_ws + WS_CC);
  unsigned short* cbs = (unsigned short*)((char*)d_ws + WS_CBS);
  int*   list = (int*)((char*)d_ws + WS_LIST);

  vq_prep1<<<512, 256, 0, stream>>>(cb, cc, loss, cnt);
  vq_prep2<<<1024, 256, 0, stream>>>(cb, cbs);
  VQQuantizer_30064771072206_kernel<<<2048, 256, 0, stream>>>(z, cbs, cc, cnt, list, out);
  vq_rescore<<<1024, 256, 0, stream>>>(z, cb, cc, cnt, list, out);
  vq_epilogue<<<2048, 256, 0, stream>>>(z, cb, loss, out);
  vq_finalize<<<1, 1, 0, stream>>>(loss, out);
}

// Round 12
// 297.025 us; speedup vs baseline: 3.5635x; 1.3049x over previous
//
#include <hip/hip_runtime.h>

typedef short s16x8 __attribute__((ext_vector_type(8)));  // 8 bf16 (guide-verified spelling)
typedef float f32x4 __attribute__((ext_vector_type(4)));

#define CODES_ELEMS 8388608   // 16*1024*512
#define N_ROWS      131072    // 16*1024*8
#define IDX_OFF     CODES_ELEMS
#define LOSS_OFF    (CODES_ELEMS + N_ROWS)

// d_ws: [0,4) loss acc; [4,8) flagged count; [64,8256) cc[2048];
// [8448,532736) cbs bf16-split tiled codebook [chunk16][seg4][ct8][lane64][8];
// [532736,1056 KB) flagged-row list (N_ROWS ints, can never overflow)
#define WS_LOSS 0
#define WS_CNT  4
#define WS_CC   64
#define WS_CBS  8448
#define WS_LIST 532736
#define MARGIN_T 0.05f   // validated r11 (absmax 0); r9/r10 validated 0.25

__device__ __forceinline__ float bf2f(unsigned short h) { return __uint_as_float(((unsigned)h) << 16); }
__device__ __forceinline__ unsigned short f2bf(float f) {   // RNE
  unsigned u = __float_as_uint(f);
  u += 0x7fffu + ((u >> 16) & 1u);
  return (unsigned short)(u >> 16);
}
// async global->LDS, 16B/lane; dest = wave-uniform base + lane*16 (r1 spelling,
// proven compiled: r1-r3 ran — their failure was u16-vs-fp32 output, not compile)
__device__ __forceinline__ void gl_lds16(const void* g, void* l) {
  __builtin_amdgcn_global_load_lds(
      (__attribute__((address_space(1))) void*)(g),
      (__attribute__((address_space(3))) void*)(l), 16, 0, 0);
}

// cc[k] = sum_d c^2 (butterfly chain identical to rounds 4-11); zero loss+cnt.
__global__ __launch_bounds__(256) void vq_prep1(const float* __restrict__ cb,
                                                float* __restrict__ cc,
                                                float* __restrict__ loss,
                                                int* __restrict__ cnt) {
  int t = threadIdx.x;
  if (blockIdx.x == 0 && t == 0) { loss[0] = 0.f; cnt[0] = 0; }
  int e = blockIdx.x * 256 + t;          // 512*256 = 2048 codes * 64 dims
  float v = cb[e];
  float s = v * v;
  #pragma unroll
  for (int m = 1; m < 64; m <<= 1) s += __shfl_xor(s, m, 64);
  if ((t & 63) == 0) cc[e >> 6] = s;
}

// bf16 split of codebook into MFMA-B-fragment tiled layout (validated r9-r11).
__global__ __launch_bounds__(256) void vq_prep2(const float* __restrict__ cb,
                                                unsigned short* __restrict__ cbs) {
  int e = blockIdx.x * 256 + threadIdx.x;   // 1024*256 = 2048 codes * 128 K-elems
  int k = e >> 7, K = e & 127;
  int s = K >> 5, rem = K & 31, q = rem >> 3, j = rem & 7;
  int d = (s < 2) ? K : (K - 64);
  float c = cb[k * 64 + d];
  unsigned short c1 = f2bf(c);
  unsigned short val = (s < 2) ? c1 : f2bf(c - bf2f(c1));  // exact residual split
  int chunk = k >> 7, ct = (k >> 4) & 7, n = k & 15;
  cbs[(((chunk * 4 + s) * 8 + ct) * 64 + (q * 16 + n)) * 8 + j] = val;
}

// Main (r11 math, restructured): block = 128 rows x 2048 codes; each wave owns
// TWO 16-row tiles so every B-fragment read feeds 2 MFMA (halves LDS traffic).
// Staging via global_load_lds (no ds_write, no VGPR round-trip).
__global__ __launch_bounds__(256) void VQQuantizer_30064771072206_kernel(
    const float* __restrict__ zf, const unsigned short* __restrict__ cbs,
    const float* __restrict__ cc, int* __restrict__ cnt, int* __restrict__ list,
    float* __restrict__ out)
{
  __shared__ __align__(16) unsigned short bt[24576];  // 49152 B: [seg6][ct8][lane64][8]
  __shared__ float cc_l[128];
  const int t = threadIdx.x, w = t >> 6, l = t & 63;
  const int col = l & 15, q = l >> 4;
  const int R0 = blockIdx.x * 128;
  const float4* zf4 = (const float4*)zf;

  // A-fragments per tile: lane holds A[m=l&15][k=q*8+j]; m -> row R0+tile*64+16w+m
  s16x8 az1[2][2], az2[2][2];   // [tile][seg]
  #pragma unroll
  for (int tile = 0; tile < 2; ++tile) {
    int row = R0 + tile * 64 + 16 * w + col;
    const float4* zr = zf4 + (size_t)row * 16;
    #pragma unroll
    for (int s = 0; s < 2; ++s) {
      float4 u0 = zr[s * 8 + q * 2];
      float4 u1 = zr[s * 8 + q * 2 + 1];
      float m2[8] = {-2.f*u0.x, -2.f*u0.y, -2.f*u0.z, -2.f*u0.w,
                     -2.f*u1.x, -2.f*u1.y, -2.f*u1.z, -2.f*u1.w};
      #pragma unroll
      for (int j = 0; j < 8; ++j) {
        unsigned short h1 = f2bf(m2[j]);
        unsigned short h2 = f2bf(m2[j] - bf2f(h1));
        az1[tile][s][j] = (short)h1;
        az2[tile][s][j] = (short)h2;
      }
    }
  }

  float v1[2][4], v2[2][4]; int i1[2][4];
  #pragma unroll
  for (int tile = 0; tile < 2; ++tile)
    #pragma unroll
    for (int r = 0; r < 4; ++r) {
      v1[tile][r] = 3.402823466e38f; v2[tile][r] = 3.402823466e38f; i1[tile][r] = 0;
    }

  for (int chunk = 0; chunk < 16; ++chunk) {
    if (chunk) __syncthreads();
    #pragma unroll
    for (int i = 0; i < 12; ++i) {        // 48 slots x 1KB, async direct-to-LDS
      int f = i * 256 + t;
      int s = f >> 9, ct_ = (f >> 6) & 7;
      int src_s = (s >= 4) ? s - 4 : s;   // segs 4,5 re-read c1 (segs 0,1)
      gl_lds16(cbs + (size_t)chunk * 16384 + (size_t)((src_s * 8 + ct_) * 64 + l) * 8,
               &bt[(size_t)((s * 8 + ct_) * 64) * 8]);
    }
    if (t < 128) cc_l[t] = cc[chunk * 128 + t];
    __syncthreads();                      // barrier drains vmcnt: staged data visible

    #pragma unroll
    for (int ct = 0; ct < 8; ++ct) {
      float nh = cc_l[ct * 16 + col];
      const unsigned short* base = &bt[(ct * 64 + l) * 8];
      s16x8 b0 = *(const s16x8*)(base + 0 * 4096);   // B-frags read ONCE,
      s16x8 b1 = *(const s16x8*)(base + 1 * 4096);   // reused by both tiles
      s16x8 b2 = *(const s16x8*)(base + 2 * 4096);
      s16x8 b3 = *(const s16x8*)(base + 3 * 4096);
      s16x8 b4 = *(const s16x8*)(base + 4 * 4096);
      s16x8 b5 = *(const s16x8*)(base + 5 * 4096);
      int code = chunk * 128 + ct * 16 + col;
      #pragma unroll
      for (int tile = 0; tile < 2; ++tile) {
        f32x4 acc; acc[0] = nh; acc[1] = nh; acc[2] = nh; acc[3] = nh;
        acc = __builtin_amdgcn_mfma_f32_16x16x32_bf16(az1[tile][0], b0, acc, 0, 0, 0);
        acc = __builtin_amdgcn_mfma_f32_16x16x32_bf16(az1[tile][1], b1, acc, 0, 0, 0);
        acc = __builtin_amdgcn_mfma_f32_16x16x32_bf16(az1[tile][0], b2, acc, 0, 0, 0);
        acc = __builtin_amdgcn_mfma_f32_16x16x32_bf16(az1[tile][1], b3, acc, 0, 0, 0);
        acc = __builtin_amdgcn_mfma_f32_16x16x32_bf16(az2[tile][0], b4, acc, 0, 0, 0);
        acc = __builtin_amdgcn_mfma_f32_16x16x32_bf16(az2[tile][1], b5, acc, 0, 0, 0);
        #pragma unroll
        for (int r = 0; r < 4; ++r) {     // ascending code ids: first-wins ties
          float d = acc[r];
          bool lt = d < v1[tile][r];
          v2[tile][r] = lt ? v1[tile][r] : fminf(v2[tile][r], d);
          i1[tile][r] = lt ? code : i1[tile][r];
          v1[tile][r] = lt ? d : v1[tile][r];
        }
      }
    }
  }

  // merge (best, idx, second) across the 16 lanes sharing each row group
  #pragma unroll
  for (int tile = 0; tile < 2; ++tile) {
    #pragma unroll
    for (int r = 0; r < 4; ++r) {
      float a = v1[tile][r], b2v = v2[tile][r]; int ia = i1[tile][r];
      #pragma unroll
      for (int m = 1; m < 16; m <<= 1) {
        float oa = __shfl_xor(a, m, 64);
        int   oi = __shfl_xor(ia, m, 64);
        float ob = __shfl_xor(b2v, m, 64);
        float hi = fmaxf(a, oa);
        b2v = fminf(fminf(b2v, ob), hi);
        bool take = (oa < a) || (oa == a && oi < ia);
        a = take ? oa : a; ia = take ? oi : ia;
      }
      v1[tile][r] = a; v2[tile][r] = b2v; i1[tile][r] = ia;
    }
    if (col == 0) {   // C/D: col=l&15, row=(l>>4)*4+r [m89, validated r9-r11]
      #pragma unroll
      for (int r = 0; r < 4; ++r) {
        int row = R0 + tile * 64 + 16 * w + q * 4 + r;
        out[IDX_OFF + row] = (float)i1[tile][r];
        if (v2[tile][r] - v1[tile][r] < MARGIN_T) {
          int p = atomicAdd(cnt, 1);
          list[p] = row;
        }
      }
    }
  }
}

// Rescore v3: 8 flagged rows per block share ONE codebook sweep (8x less L2
// traffic). Per (row,code) chain identical to validated r10/r11: zz seq-d,
// dot seq-d, dist=(zz-2a)+cc, ascending-code first-wins, lowest-index merge.
__global__ __launch_bounds__(256) void vq_rescore(
    const float* __restrict__ zf, const float* __restrict__ cb,
    const float* __restrict__ cc, const int* __restrict__ cnt,
    const int* __restrict__ list, float* __restrict__ out)
{
  __shared__ __align__(16) float zl[8][68];
  __shared__ float zz_l[8];
  __shared__ int   rows_s[8];
  __shared__ float rv[4][8];
  __shared__ int   ri[4][8];
  const int t = threadIdx.x, w = t >> 6, l = t & 63;
  const int count = cnt[0];
  const float4* cb4 = (const float4*)cb;

  for (int itb = blockIdx.x; itb * 8 < count; itb += 1024) {
    if (itb != (int)blockIdx.x) __syncthreads();
    if (t < 8) {
      int ii = itb * 8 + t;
      rows_s[t] = list[ii < count ? ii : count - 1];  // tail dup: benign rewrite
    }
    __syncthreads();
    if (t < 128) {
      int r = t >> 4, dq = t & 15;
      *(float4*)&zl[r][dq * 4] = ((const float4*)zf)[(size_t)rows_s[r] * 16 + dq];
    }
    __syncthreads();
    if (t < 8) {                          // zz: sequential-d np chain
      float s = 0.f;
      for (int d = 0; d < 64; ++d) { float v = zl[t][d]; s += v * v; }
      zz_l[t] = s;
    }
    __syncthreads();

    float bv[8]; int bi[8];
    #pragma unroll
    for (int r = 0; r < 8; ++r) { bv[r] = 3.402823466e38f; bi[r] = 0; }
    #pragma unroll 1
    for (int o = 0; o < 8; ++o) {         // thread's codes ascending: o*256+t
      int c = o * 256 + t;
      const float4* cr = cb4 + (size_t)c * 16;
      float a[8];
      #pragma unroll
      for (int r = 0; r < 8; ++r) a[r] = 0.f;
      #pragma unroll
      for (int dq = 0; dq < 16; ++dq) {
        float4 cv = cr[dq];
        #pragma unroll
        for (int r = 0; r < 8; ++r) {
          float4 z4 = *(const float4*)&zl[r][dq * 4];   // broadcast (free)
          a[r] += z4.x * cv.x;            // ascending d, one fused chain per row
          a[r] += z4.y * cv.y;
          a[r] += z4.z * cv.z;
          a[r] += z4.w * cv.w;
        }
      }
      float ccv = cc[c];
      #pragma unroll
      for (int r = 0; r < 8; ++r) {
        float t0 = zz_l[r] - 2.0f * a[r];
        float dist = t0 + ccv;
        if (dist < bv[r]) { bv[r] = dist; bi[r] = c; }
      }
    }
    // 64-lane merge, then 4-wave merge; (min value, lowest index) semantics
    #pragma unroll
    for (int r = 0; r < 8; ++r) {
      float v = bv[r]; int idx = bi[r];
      #pragma unroll
      for (int m = 1; m < 64; m <<= 1) {
        float ov = __shfl_xor(v, m, 64); int oi = __shfl_xor(idx, m, 64);
        if (ov < v || (ov == v && oi < idx)) { v = ov; idx = oi; }
      }
      if (l == 0) { rv[w][r] = v; ri[w][r] = idx; }
    }
    __syncthreads();
    if (t < 8) {
      float fv = rv[0][t]; int fi = ri[0][t];
      #pragma unroll
      for (int k = 1; k < 4; ++k) {
        if (rv[k][t] < fv || (rv[k][t] == fv && ri[k][t] < fi)) { fv = rv[k][t]; fi = ri[k][t]; }
      }
      out[IDX_OFF + rows_s[t]] = (float)fi;
    }
  }
}

// codes = zg + (zq - zg), commit loss fp32 (validated epilogue, idx from out).
__global__ __launch_bounds__(256) void vq_epilogue(
    const float* __restrict__ zf, const float* __restrict__ cb,
    float* __restrict__ loss, float* __restrict__ out)
{
  __shared__ int idxb[64];
  __shared__ float wsum[4];
  int t = threadIdx.x;
  int R0 = blockIdx.x * 64;
  if (t < 64) idxb[t] = (int)out[IDX_OFF + R0 + t];
  __syncthreads();
  const float4* zf4 = (const float4*)zf;
  const float4* cb4 = (const float4*)cb;
  float4* out4 = (float4*)out;
  float lsum = 0.f;
  #pragma unroll
  for (int i = 0; i < 4; ++i) {
    int f = i * 256 + t;
    int row = f >> 4, dq = f & 15;
    int k = idxb[row];
    float4 qv = cb4[(size_t)k * 16 + dq];
    float4 zv = zf4[(size_t)(R0 + row) * 16 + dq];
    float dx = qv.x - zv.x, dy = qv.y - zv.y, dz = qv.z - zv.z, dw = qv.w - zv.w;
    float4 st; st.x = zv.x + dx; st.y = zv.y + dy; st.z = zv.z + dz; st.w = zv.w + dw;
    out4[(size_t)(R0 + row) * 16 + dq] = st;
    lsum += dx * dx; lsum += dy * dy; lsum += dz * dz; lsum += dw * dw;
  }
  #pragma unroll
  for (int m = 1; m < 64; m <<= 1) lsum += __shfl_xor(lsum, m, 64);
  if ((t & 63) == 0) wsum[t >> 6] = lsum;
  __syncthreads();
  if (t == 0) atomicAdd(loss, wsum[0] + wsum[1] + wsum[2] + wsum[3]);
}

__global__ void vq_finalize(const float* __restrict__ loss, float* __restrict__ out) {
  out[LOSS_OFF] = loss[0] * (1.f / 8388608.f);
}

extern "C" void kernel_launch(void* const* d_in, const int* in_sizes, int n_in,
                              void* d_out, int out_size, void* d_ws, size_t ws_size,
                              hipStream_t stream) {
  const float* z  = (const float*)d_in[0];
  const float* cb = (const float*)d_in[1];
  float* out = (float*)d_out;
  float* loss = (float*)((char*)d_ws + WS_LOSS);
  int*   cnt  = (int*)((char*)d_ws + WS_CNT);
  float* cc   = (float*)((char*)d_ws + WS_CC);
  unsigned short* cbs = (unsigned short*)((char*)d_ws + WS_CBS);
  int*   list = (int*)((char*)d_ws + WS_LIST);

  vq_prep1<<<512, 256, 0, stream>>>(cb, cc, loss, cnt);
  vq_prep2<<<1024, 256, 0, stream>>>(cb, cbs);
  VQQuantizer_30064771072206_kernel<<<1024, 256, 0, stream>>>(z, cbs, cc, cnt, list, out);
  vq_rescore<<<1024, 256, 0, stream>>>(z, cb, cc, cnt, list, out);
  vq_epilogue<<<2048, 256, 0, stream>>>(z, cb, loss, out);
  vq_finalize<<<1, 1, 0, stream>>>(loss, out);
}